// Round 1
// 1280.952 us; speedup vs baseline: 1.0682x; 1.0682x over previous
//
#include <hip/hip_runtime.h>
#include <math.h>

// ---------------- types / helpers ----------------
typedef __bf16 bf16x8 __attribute__((ext_vector_type(8)));
typedef float floatx4 __attribute__((ext_vector_type(4)));
typedef unsigned short ushortx4 __attribute__((ext_vector_type(4)));
typedef unsigned short ushortx8 __attribute__((ext_vector_type(8)));

#define DEV __device__ __forceinline__

DEV unsigned short f2bf(float f){
  unsigned int u = __float_as_uint(f);
  return (unsigned short)((u + 0x7fffu + ((u >> 16) & 1u)) >> 16);  // RNE
}
DEV float bf2f(unsigned short h){ return __uint_as_float(((unsigned int)h) << 16); }

DEV void gld16(const void* g, void* l){
  __builtin_amdgcn_global_load_lds((const __attribute__((address_space(1))) void*)g,
                                   (__attribute__((address_space(3))) void*)l, 16, 0, 0);
}
DEV floatx4 mfma16(bf16x8 a, bf16x8 b, floatx4 c){
  return __builtin_amdgcn_mfma_f32_16x16x32_bf16(a, b, c, 0, 0, 0);
}

#define NH 32
#define HD 128
#define QL 512
#define KVL 1024
#define HID 4096

// ---------------- 1. hidden fp32 -> bf16 ----------------
__global__ void k_convert(const float* __restrict__ src, unsigned short* __restrict__ dst){
  size_t u = (size_t)blockIdx.x*256 + threadIdx.x;
  float4 a = ((const float4*)src)[2*u];
  float4 b = ((const float4*)src)[2*u+1];
  ushortx8 o;
  o[0]=f2bf(a.x); o[1]=f2bf(a.y); o[2]=f2bf(a.z); o[3]=f2bf(a.w);
  o[4]=f2bf(b.x); o[5]=f2bf(b.y); o[6]=f2bf(b.z); o[7]=f2bf(b.w);
  ((ushortx8*)dst)[u] = o;
}

// ---------------- 2. weights fp32 [K][N] -> bf16 [N][K] ----------------
__global__ void k_transpose_w(const float* __restrict__ W0, const float* __restrict__ W1,
                              const float* __restrict__ W2, const float* __restrict__ W3,
                              unsigned short* __restrict__ Wt){
  int bx = blockIdx.x, by = blockIdx.y, z = blockIdx.z;
  const float* src = (z==0)?W0:(z==1)?W1:(z==2)?W2:W3;
  __shared__ float t[64][65];
  int tid = threadIdx.x;
  int rr = tid >> 4, cc = tid & 15;
  #pragma unroll
  for (int p = 0; p < 4; ++p){
    int row = p*16 + rr;
    float4 v = *(const float4*)(src + (size_t)(by*64+row)*HID + bx*64 + cc*4);
    t[row][cc*4+0]=v.x; t[row][cc*4+1]=v.y; t[row][cc*4+2]=v.z; t[row][cc*4+3]=v.w;
  }
  __syncthreads();
  unsigned short* dst = Wt + (size_t)z*HID*HID;
  #pragma unroll
  for (int p = 0; p < 4; ++p){
    int orow = p*16 + rr;
    ushortx4 o;
    o[0]=f2bf(t[cc*4+0][orow]); o[1]=f2bf(t[cc*4+1][orow]);
    o[2]=f2bf(t[cc*4+2][orow]); o[3]=f2bf(t[cc*4+3][orow]);
    *(ushortx4*)(dst + (size_t)(bx*64+orow)*HID + by*64 + cc*4) = o;
  }
}

// ---------------- 3/8. GEMM: C[M][N] = A[M][K] * Bt[N][K] ----------------
// 256x256 tile, BK=64, 8 waves (2M x 4N), 8-phase schedule with counted
// vmcnt(6) (loads stay in flight across barriers), per-row XOR LDS swizzle
// (conflict-free ds_read_b128), s_setprio around MFMA clusters.
// Staging runs 7 half-tiles (1.75 K-tiles) ahead; slot-overwrite safety:
//   per tile t, buf[t&1] overwrites (for t+2) issue at phases 1/2/3 for
//   slots B0/B1/A0; reads of those slots occur at phases 0 / 0 / 0-2 only.
template<int MODE, int NTILES>
__global__ __launch_bounds__(512, 2) void k_gemm(
    const unsigned short* __restrict__ A, const unsigned short* __restrict__ Bt,
    float* __restrict__ Cf, unsigned short* __restrict__ Qr,
    unsigned short* __restrict__ Kf, unsigned short* __restrict__ Vtmp,
    int K, int N)
{
  __shared__ __align__(16) unsigned short As[2][256*64];
  __shared__ __align__(16) unsigned short Bs[2][256*64];
  const int tid = threadIdx.x;
  const int wave = tid >> 6, lane = tid & 63;
  const int lm = lane & 15, quad = lane >> 4;
  const int wm = wave >> 2, wn = wave & 3;       // 2 x 4 wave grid

  const int lin = blockIdx.x;
  const int xcd = lin & 7, loc = lin >> 3;       // bijective: grid%8 == 0
  const int bm = xcd*2 + loc / NTILES;
  const int bn = loc % NTILES;
  const int NT = K >> 6;

  // ---- staging addresses (pre-swizzled global source, linear LDS dest) ----
  const unsigned short* gA[2]; const unsigned short* gB[2];
  unsigned short* lA[2]; unsigned short* lB[2];
  #pragma unroll
  for (int j=0;j<2;j++){
    int rh = (wave*2 + j)*8 + (lane >> 3);       // row within 128-row half
    int cswz = ((lane & 7) ^ (rh & 7)) * 8;      // swizzled 16B chunk (shorts)
    gA[j] = A  + (size_t)(bm*256 + rh)*K + cswz;
    gB[j] = Bt + (size_t)(bn*256 + rh)*K + cswz;
    lA[j] = &As[0][0] + (wave*2 + j)*512;        // 1KB stripe per issue
    lB[j] = &Bs[0][0] + (wave*2 + j)*512;
  }
  // stage one 128x64 half-tile: kind 0=B0 1=B1 2=A0 3=A1, into buf[u&1]
  auto STAGE = [&](int u, int kind){
    const int bo  = (u & 1) * 16384 + (kind & 1) * 8192;       // shorts
    const size_t go = (size_t)(kind & 1) * 128 * (size_t)K + (size_t)u * 64;
    if (kind < 2){
      #pragma unroll
      for (int j=0;j<2;j++) gld16(gB[j] + go, lB[j] + bo);
    } else {
      #pragma unroll
      for (int j=0;j<2;j++) gld16(gA[j] + go, lA[j] + bo);
    }
  };

  // ---- fragment read bases (read-side swizzle matches staging) ----
  const int rbA = (wm*128 + lm)*64;
  const int rbB = (wn*64  + lm)*64;
  const int cx0 = ( quad      ^ (lm & 7))*8;
  const int cx1 = ((4 + quad) ^ (lm & 7))*8;

  floatx4 acc[8][4];
  #pragma unroll
  for (int i=0;i<8;i++)
    #pragma unroll
    for (int j=0;j<4;j++) acc[i][j] = (floatx4){0.f,0.f,0.f,0.f};

  // ---- prologue: tile0 fully + tile1 {B0,B1,A0}; tile1.A1 staged in t=0 p=0
  STAGE(0,0); STAGE(0,1); STAGE(0,2); STAGE(0,3);
  asm volatile("s_waitcnt vmcnt(4)" ::: "memory");
  STAGE(1,0); STAGE(1,1); STAGE(1,2);
  asm volatile("s_waitcnt vmcnt(6)" ::: "memory");   // tile 0 resident
  __builtin_amdgcn_sched_barrier(0);
  __builtin_amdgcn_s_barrier();
  __builtin_amdgcn_sched_barrier(0);

  bf16x8 afr[8][2], bfr[4][2];

  for (int t = 0; t < NT; ++t){
    const unsigned short* Ab = &As[t&1][0];
    const unsigned short* Bb = &Bs[t&1][0];
    #pragma unroll
    for (int p = 0; p < 4; ++p){
      // ---- ds-read register subtiles + issue one half-tile prefetch ----
      if (p == 0){
        #pragma unroll
        for (int n=0;n<4;n++){
          bfr[n][0] = *(const bf16x8*)(Bb + rbB + n*1024 + cx0);
          bfr[n][1] = *(const bf16x8*)(Bb + rbB + n*1024 + cx1);
        }
        #pragma unroll
        for (int m=0;m<2;m++){
          afr[m][0] = *(const bf16x8*)(Ab + rbA + m*1024 + cx0);
          afr[m][1] = *(const bf16x8*)(Ab + rbA + m*1024 + cx1);
        }
        if (t+1 < NT) STAGE(t+1, 3);            // A1(t+1) -> buf[(t+1)&1]
      } else if (p == 1){
        #pragma unroll
        for (int m=2;m<4;m++){
          afr[m][0] = *(const bf16x8*)(Ab + rbA + m*1024 + cx0);
          afr[m][1] = *(const bf16x8*)(Ab + rbA + m*1024 + cx1);
        }
        if (t+2 < NT) STAGE(t+2, 0);            // B0(t+2) -> buf[t&1]
      } else if (p == 2){
        #pragma unroll
        for (int m=4;m<8;m++){
          afr[m][0] = *(const bf16x8*)(Ab + rbA + m*1024 + cx0);
          afr[m][1] = *(const bf16x8*)(Ab + rbA + m*1024 + cx1);
        }
        if (t+2 < NT) STAGE(t+2, 1);            // B1(t+2) -> buf[t&1]
      } else {
        if (t+2 < NT) STAGE(t+2, 2);            // A0(t+2) -> buf[t&1]
      }
      __builtin_amdgcn_sched_barrier(0);
      __builtin_amdgcn_s_barrier();
      __builtin_amdgcn_sched_barrier(0);
      // ---- 16 MFMA: m-pair {2p,2p+1} x 4n x 2k ----
      __builtin_amdgcn_s_setprio(1);
      #pragma unroll
      for (int mm = 2*p; mm < 2*p + 2; ++mm)
        #pragma unroll
        for (int n = 0; n < 4; ++n){
          floatx4 a = acc[mm][n];
          a = mfma16(afr[mm][0], bfr[n][0], a);
          a = mfma16(afr[mm][1], bfr[n][1], a);
          acc[mm][n] = a;
        }
      __builtin_amdgcn_s_setprio(0);
      if (p == 3){
        // once per K-tile: next tile must be resident past this barrier;
        // keep 3 half-tiles (6 loads) in flight. Drain fully only at tail.
        if (t < NT-2)       asm volatile("s_waitcnt vmcnt(6)" ::: "memory");
        else if (t == NT-2) asm volatile("s_waitcnt vmcnt(0)" ::: "memory");
      }
      __builtin_amdgcn_sched_barrier(0);
      __builtin_amdgcn_s_barrier();
      __builtin_amdgcn_sched_barrier(0);
    }
  }

  // ---- epilogue ----
  #pragma unroll
  for (int mi=0;mi<8;mi++){
    #pragma unroll
    for (int ni=0;ni<4;ni++){
      #pragma unroll
      for (int r=0;r<4;r++){
        int trow = bm*256 + wm*128 + mi*16 + quad*4 + r;
        int col  = bn*256 + wn*64  + ni*16 + lm;
        float val = acc[mi][ni][r];
        if (MODE == 0){
          Cf[(size_t)trow*N + col] = val;
        } else {
          unsigned short bv = f2bf(val);
          int b = trow >> 9, qi = trow & 511;
          if (col < 4096){
            int hh = col >> 7, hd = col & 127;
            Qr[((size_t)(b*NH + hh)*QL + qi)*HD + hd] = bv;
          } else if (col < 8192){
            int cc2 = col - 4096; int hh = cc2 >> 7, hd = cc2 & 127;
            Kf[((size_t)(b*NH + hh)*KVL + 512 + qi)*HD + hd] = bv;
          } else {
            Vtmp[(size_t)trow*HID + (col - 8192)] = bv;
          }
        }
      }
    }
  }
}

// ---------------- 4. RoPE in-place on Qr and Kf[512:] ----------------
__global__ void k_rope(unsigned short* __restrict__ Qr, unsigned short* __restrict__ Kf,
                       const int* __restrict__ pos_ids){
  int u = blockIdx.x*256 + threadIdx.x;
  int i = u & 63;
  int grp = u >> 6;
  int qi = grp & 511;
  int h = (grp >> 9) & 31;
  int b = grp >> 14;
  int t = b*QL + qi;
  int pos = pos_ids[t];
  float ang = (float)pos * exp2f((float)i * -0.20762050593046014f);
  float s, c;
  sincosf(ang, &s, &c);
  unsigned short* qp = Qr + ((size_t)(b*NH + h)*QL + qi)*HD;
  float x = bf2f(qp[i]), y = bf2f(qp[i+64]);
  qp[i]    = f2bf(x*c - y*s);
  qp[i+64] = f2bf(y*c + x*s);
  unsigned short* kp = Kf + ((size_t)(b*NH + h)*KVL + 512 + qi)*HD;
  x = bf2f(kp[i]); y = bf2f(kp[i+64]);
  kp[i]    = f2bf(x*c - y*s);
  kp[i+64] = f2bf(y*c + x*s);
}

// ---------------- 5. history K gather ----------------
__global__ void k_gather_k(const float* __restrict__ k_cache, const int* __restrict__ block_offsets,
                           unsigned short* __restrict__ Kf){
  int u = blockIdx.x*256 + threadIdx.x;
  int c4 = u & 31;
  int h  = (u >> 5) & 31;
  int kv = (u >> 10) & 511;
  int b  = u >> 19;
  int blk = block_offsets[b*16 + (kv >> 6)];
  int slot = kv & 63;
  float4 v = *(const float4*)(k_cache + ((size_t)(blk*64 + slot)*NH + h)*HD + c4*4);
  ushortx4 o; o[0]=f2bf(v.x); o[1]=f2bf(v.y); o[2]=f2bf(v.z); o[3]=f2bf(v.w);
  *(ushortx4*)(Kf + ((size_t)(b*NH + h)*KVL + kv)*HD + c4*4) = o;
}

// ---------------- 6. V transpose ----------------
__global__ void k_transpose_v(const float* __restrict__ v_cache, const unsigned short* __restrict__ Vtmp,
                              const int* __restrict__ block_offsets, unsigned short* __restrict__ Vt){
  int kvt = blockIdx.x, h = blockIdx.y, b = blockIdx.z;
  __shared__ __align__(16) unsigned short tt[64*132];
  int tid = threadIdx.x;
  #pragma unroll
  for (int p=0;p<8;p++){
    int cc = p*256 + tid;
    int slot = cc >> 5, c4 = cc & 31;
    ushortx4 val;
    if (kvt < 8){
      int blk = block_offsets[b*16 + kvt];
      float4 f = *(const float4*)(v_cache + ((size_t)(blk*64 + slot)*NH + h)*HD + c4*4);
      val[0]=f2bf(f.x); val[1]=f2bf(f.y); val[2]=f2bf(f.z); val[3]=f2bf(f.w);
    } else {
      val = *(const ushortx4*)(Vtmp + (size_t)(b*QL + (kvt-8)*64 + slot)*HID + h*HD + c4*4);
    }
    *(ushortx4*)(tt + slot*132 + c4*4) = val;
  }
  __syncthreads();
  #pragma unroll
  for (int p=0;p<8;p++){
    int cc = p*256 + tid;
    int hd = cc >> 4, s4 = cc & 15;
    ushortx4 o;
    o[0]=tt[(s4*4+0)*132 + hd];
    o[1]=tt[(s4*4+1)*132 + hd];
    o[2]=tt[(s4*4+2)*132 + hd];
    o[3]=tt[(s4*4+3)*132 + hd];
    *(ushortx4*)(Vt + ((size_t)(b*NH + h)*HD + hd)*KVL + kvt*64 + s4*4) = o;
  }
}

// ---------------- 7. flash attention (pipelined) ----------------
// 256 thr / 4 waves, 32 Q-rows per wave, KV tiles of 128.
// K double-buffered; V(j) + K(j+1) prefetch issued before QK(j)/softmax(j) so
// the mid-tile barrier drain overlaps compute. P stored row-permuted (sigma:
// q*4+r -> r*4+q) at stride 144 -> conflict-free b16 writes (quad banks 0/8/16/24).
DEV void stage128(const char* srcBase, unsigned short* lds, int rowStrideBytes, int wave, int lane){
  #pragma unroll
  for (int jj=0;jj<8;jj++){
    int issue = wave*8 + jj;
    int row = issue*4 + (lane >> 4);
    int c = (lane & 15) ^ (row & 15);
    gld16(srcBase + (size_t)row*rowStrideBytes + c*16, lds + issue*512);
  }
}
DEV bf16x8 frag_swz(const unsigned short* lds, int row, int ks, int quad){
  int c = (ks*4 + quad) ^ (row & 15);
  return *(const bf16x8*)(lds + row*128 + c*8);
}

#define PSTR 144

__global__ __launch_bounds__(256, 1) void k_attn(
    const unsigned short* __restrict__ Qr, const unsigned short* __restrict__ Kf,
    const unsigned short* __restrict__ Vt, unsigned short* __restrict__ AO)
{
  int qt = blockIdx.x, h = blockIdx.y, b = blockIdx.z;
  int tid = threadIdx.x, wave = tid >> 6, lane = tid & 63;
  int lm = lane & 15, quad = lane >> 4;
  __shared__ __align__(16) unsigned short KS[2][128*128];
  __shared__ __align__(16) unsigned short VS[128*128];
  __shared__ __align__(16) unsigned short PS[4*32*PSTR];
  const char* Qbase = (const char*)(Qr + ((size_t)(b*NH + h)*QL + qt*128)*HD);
  const char* Kbase = (const char*)(Kf + ((size_t)(b*NH + h)*KVL)*HD);
  const char* Vbase = (const char*)(Vt + ((size_t)(b*NH + h)*HD)*KVL);

  // prologue: Q through VS, K(0) into KS[0]
  stage128(Qbase, VS, 256, wave, lane);
  stage128(Kbase, KS[0], 256, wave, lane);
  __syncthreads();
  bf16x8 qf[2][4];
  #pragma unroll
  for (int mt=0;mt<2;mt++)
    #pragma unroll
    for (int ks=0;ks<4;ks++)
      qf[mt][ks] = frag_swz(VS, wave*32 + mt*16 + lm, ks, quad);
  __syncthreads();

  float m_st[2][4], l_st[2][4];
  floatx4 o[2][8];
  #pragma unroll
  for (int mt=0;mt<2;mt++){
    #pragma unroll
    for (int r=0;r<4;r++){ m_st[mt][r] = -3.0e38f; l_st[mt][r] = 0.f; }
    #pragma unroll
    for (int nt=0;nt<8;nt++) o[mt][nt] = (floatx4){0.f,0.f,0.f,0.f};
  }
  unsigned short* myP = PS + wave*(32*PSTR);
  const int sig = ((lm & 3) << 2) | (lm >> 2);   // read-side sigma(lm)
  const float scale = 0.08838834764831845f;
  int ntiles = qt + 5;

  for (int j=0;j<ntiles;j++){
    const unsigned short* cur = KS[j & 1];
    unsigned short* nxt = (unsigned short*)KS[(j+1) & 1];
    // prefetch V(j) and K(j+1); drained at the mid-tile barrier below
    stage128(Vbase + (size_t)j*256, VS, 2048, wave, lane);
    if (j+1 < ntiles) stage128(Kbase + (size_t)(j+1)*128*256, nxt, 256, wave, lane);

    // QK^T from cur (ready since previous barrier)
    floatx4 s[2][8];
    #pragma unroll
    for (int nt=0;nt<8;nt++){
      bf16x8 kf4[4];
      #pragma unroll
      for (int ks=0;ks<4;ks++) kf4[ks] = frag_swz(cur, nt*16 + lm, ks, quad);
      #pragma unroll
      for (int mt=0;mt<2;mt++){
        floatx4 a = (floatx4){0.f,0.f,0.f,0.f};
        #pragma unroll
        for (int ks=0;ks<4;ks++) a = mfma16(qf[mt][ks], kf4[ks], a);
        s[mt][nt] = a;
      }
    }
    bool diag = (j == qt + 4);
    #pragma unroll
    for (int mt=0;mt<2;mt++){
      #pragma unroll
      for (int r=0;r<4;r++){
        int rowl = wave*32 + mt*16 + quad*4 + r;
        float mx = -3.0e38f;
        #pragma unroll
        for (int nt=0;nt<8;nt++){
          float v = s[mt][nt][r] * scale;
          if (diag && (nt*16 + lm > rowl)) v = -3.0e38f;
          s[mt][nt][r] = v;
          mx = fmaxf(mx, v);
        }
        mx = fmaxf(mx, __shfl_xor(mx, 1));
        mx = fmaxf(mx, __shfl_xor(mx, 2));
        mx = fmaxf(mx, __shfl_xor(mx, 4));
        mx = fmaxf(mx, __shfl_xor(mx, 8));
        float mold = m_st[mt][r];
        float mnew = fmaxf(mold, mx);
        float alpha = __expf(mold - mnew);
        m_st[mt][r] = mnew;
        float rs = 0.f;
        #pragma unroll
        for (int nt=0;nt<8;nt++){
          float p = __expf(s[mt][nt][r] - mnew);
          s[mt][nt][r] = p;
          rs += p;
        }
        rs += __shfl_xor(rs, 1);
        rs += __shfl_xor(rs, 2);
        rs += __shfl_xor(rs, 4);
        rs += __shfl_xor(rs, 8);
        l_st[mt][r] = l_st[mt][r]*alpha + rs;
        #pragma unroll
        for (int nt=0;nt<8;nt++) o[mt][nt][r] *= alpha;
      }
    }
    // P write (sigma layout): logical row quad*4+r stored at r*4+quad
    #pragma unroll
    for (int mt=0;mt<2;mt++)
      #pragma unroll
      for (int nt=0;nt<8;nt++)
        #pragma unroll
        for (int r=0;r<4;r++)
          myP[(mt*16 + r*4 + quad)*PSTR + nt*16 + lm] = f2bf(s[mt][nt][r]);

    __syncthreads();   // drains V(j), K(j+1); P visible per-wave anyway

    // hoisted P fragments (A-layout): logical row lm -> stored row sig
    bf16x8 pf[2][4];
    #pragma unroll
    for (int mt=0;mt<2;mt++)
      #pragma unroll
      for (int ks=0;ks<4;ks++)
        pf[mt][ks] = *(const bf16x8*)(myP + (mt*16 + sig)*PSTR + ks*32 + quad*8);

    // O += P * V
    #pragma unroll
    for (int nt=0;nt<8;nt++){
      bf16x8 vf4[4];
      #pragma unroll
      for (int ks=0;ks<4;ks++) vf4[ks] = frag_swz(VS, nt*16 + lm, ks, quad);
      #pragma unroll
      for (int mt=0;mt<2;mt++){
        floatx4 a = o[mt][nt];
        #pragma unroll
        for (int ks=0;ks<4;ks++) a = mfma16(pf[mt][ks], vf4[ks], a);
        o[mt][nt] = a;
      }
    }
    __syncthreads();   // protect VS reuse next tile
  }

  #pragma unroll
  for (int mt=0;mt<2;mt++){
    #pragma unroll
    for (int r=0;r<4;r++){
      float inv = 1.f / l_st[mt][r];
      #pragma unroll
      for (int nt=0;nt<8;nt++){
        int trow = b*QL + qt*128 + wave*32 + mt*16 + quad*4 + r;
        int col = h*HD + nt*16 + lm;
        AO[(size_t)trow*HID + col] = f2bf(o[mt][nt][r] * inv);
      }
    }
  }
}

// ---------------- launch ----------------
extern "C" void kernel_launch(void* const* d_in, const int* in_sizes, int n_in,
                              void* d_out, int out_size, void* d_ws, size_t ws_size,
                              hipStream_t stream) {
  const float* hidden   = (const float*)d_in[0];
  const float* Wq       = (const float*)d_in[1];
  const float* Wk       = (const float*)d_in[2];
  const float* Wv       = (const float*)d_in[3];
  const float* Wo       = (const float*)d_in[4];
  const float* k_cache  = (const float*)d_in[5];
  const float* v_cache  = (const float*)d_in[6];
  const int* block_offsets = (const int*)d_in[7];
  const int* pos_ids    = (const int*)d_in[8];
  float* out = (float*)d_out;

  char* ws = (char*)d_ws;
  unsigned short* hb   = (unsigned short*)(ws + 0x0);
  unsigned short* Wt   = (unsigned short*)(ws + 0x2000000);
  unsigned short* Qr   = (unsigned short*)(ws + 0xA000000);
  unsigned short* Kf   = (unsigned short*)(ws + 0xC000000);
  unsigned short* Vt   = (unsigned short*)(ws + 0x10000000);
  unsigned short* Vtmp = (unsigned short*)(ws + 0x14000000);
  unsigned short* AO   = hb;

  k_convert<<<8192, 256, 0, stream>>>(hidden, hb);
  k_transpose_w<<<dim3(64,64,4), 256, 0, stream>>>(Wq, Wk, Wv, Wo, Wt);
  // 16 bm-tiles x 48 bn-tiles = 768 blocks (768 % 8 == 0 -> simple XCD swizzle)
  k_gemm<1,48><<<768, 512, 0, stream>>>(hb, Wt, nullptr, Qr, Kf, Vtmp, 4096, 12288);
  k_rope<<<32768, 256, 0, stream>>>(Qr, Kf, pos_ids);
  k_gather_k<<<16384, 256, 0, stream>>>(k_cache, block_offsets, Kf);
  k_transpose_v<<<dim3(16,32,8), 256, 0, stream>>>(v_cache, Vtmp, block_offsets, Vt);
  k_attn<<<dim3(4,32,8), 256, 0, stream>>>(Qr, Kf, Vt, AO);
  // 16 x 16 = 256 blocks
  k_gemm<0,16><<<256, 512, 0, stream>>>(AO, Wt + (size_t)3*4096*4096, out,
                                        nullptr, nullptr, nullptr, 4096, 4096);
}